// Round 3
// baseline (147.018 us; speedup 1.0000x reference)
//
#include <hip/hip_runtime.h>
#include <stdint.h>

#define NBITS 57
#define RPB   256                       // rows per block
#define WPB   ((RPB * NBITS) / 64)      // 228 64-word windows per full block

__global__ __launch_bounds__(256) void lzc57_kernel(const uint32_t* __restrict__ X,
                                                    float* __restrict__ out,
                                                    int nrows) {
    __shared__ unsigned long long s_mask[WPB + 1];  // 1832 B
    __shared__ float s_out[RPB * 6];                // 6144 B
    const int tid  = threadIdx.x;
    const int wave = tid >> 6;
    const int lane = tid & 63;
    const int row0 = blockIdx.x * RPB;
    const int rows = min(RPB, nrows - row0);
    const uint32_t* src = X + (size_t)row0 * NBITS;

    // ---- phase 1: ballot transpose — one u64 word-order mask per 64-word window ----
    if (rows == RPB) {
        const int base = wave * 57;                 // 228 windows, 57 contiguous per wave
        #pragma unroll 8
        for (int i = 0; i < 57; ++i) {
            const int win = base + i;
            const uint32_t x = src[win * 64 + lane];        // coalesced 256B/wave
            const unsigned long long b = __ballot(x != 0u); // bit l = word win*64+l nonzero
            if (lane == 0) s_mask[win] = b;
        }
    } else {
        const int wlimit = rows * NBITS;
        const int W = (wlimit + 63) >> 6;
        for (int win = wave; win < W; win += 4) {
            const int w = win * 64 + lane;
            const uint32_t x = (w < wlimit) ? src[w] : 0u;
            const unsigned long long b = __ballot(x != 0u);
            if (lane == 0) s_mask[win] = b;
        }
    }
    __syncthreads();

    // ---- phase 2: per-row LZC via 57-bit funnel extract ----
    if (tid < rows) {
        const int bitpos = tid * NBITS;
        const int m = bitpos >> 6;
        const int s = bitpos & 63;
        const unsigned long long lo = s_mask[m];
        const unsigned long long hi = s_mask[m + 1];  // if unwritten, masked off below (s<8)
        unsigned long long v = s ? ((lo >> s) | (hi << (64 - s))) : lo;
        v &= (1ull << NBITS) - 1ull;
        const int lzc = v ? (__ffsll(v) - 1) : NBITS;
        #pragma unroll
        for (int j = 0; j < 6; ++j)
            s_out[tid * 6 + j] = (float)((lzc >> (5 - j)) & 1);
    }
    __syncthreads();

    // ---- phase 3: coalesced float4 store of staged output ----
    float* dstf = out + (size_t)row0 * 6;
    const int nout = rows * 6;
    const int no4 = nout >> 2;
    const float4* s4 = (const float4*)s_out;
    float4* o4 = (float4*)dstf;
    for (int i = tid; i < no4; i += RPB) o4[i] = s4[i];
    for (int i = (no4 << 2) + tid; i < nout; i += RPB) dstf[i] = s_out[i];
}

extern "C" void kernel_launch(void* const* d_in, const int* in_sizes, int n_in,
                              void* d_out, int out_size, void* d_ws, size_t ws_size,
                              hipStream_t stream) {
    const uint32_t* X = (const uint32_t*)d_in[0];
    float* out = (float*)d_out;
    const int nrows = in_sizes[0] / NBITS;
    const int blocks = (nrows + RPB - 1) / RPB;
    lzc57_kernel<<<blocks, RPB, 0, stream>>>(X, out, nrows);
}

// Round 4
// 108.995 us; speedup vs baseline: 1.3488x; 1.3488x over previous
//
#include <hip/hip_runtime.h>
#include <stdint.h>

#define NBITS  57
#define RPB    256                    // rows per chunk
#define ROUNDS 57                     // 64-uint4 async-load rounds per chunk (3648 uint4)

typedef const __attribute__((address_space(1))) void gvoid_t;
typedef __attribute__((address_space(3))) void       lvoid_t;

__global__ __launch_bounds__(256) void lzc57_kernel(const uint32_t* __restrict__ X,
                                                    float* __restrict__ out,
                                                    int nrows, int nchunks) {
    __shared__ uint32_t s_in[2][RPB * NBITS];   // 2 x 58368 B = 116736 B -> 1 block/CU
    const int tid  = threadIdx.x;
    const int wave = tid >> 6;
    const int lane = tid & 63;

    // balanced contiguous chunk range for this block
    const int nb = gridDim.x;
    const int b  = blockIdx.x;
    const int q  = nchunks / nb, r = nchunks % nb;
    const int c0 = b * q + min(b, r);
    const int c1 = c0 + q + (b < r ? 1 : 0);

    // issue one chunk's async loads: rounds rr = wave + 4*i (wave0: 15, waves1-3: 14)
    #define ISSUE(c, buf)                                                          \
        do {                                                                       \
            const uint4* s4_ = (const uint4*)(X + (size_t)(c) * RPB * NBITS);      \
            uint32_t* lb_ = &s_in[buf][0];                                         \
            _Pragma("unroll")                                                      \
            for (int i_ = 0; i_ < 15; ++i_) {                                      \
                const int rr_ = wave + 4 * i_;                                     \
                if (rr_ < ROUNDS)                                                  \
                    __builtin_amdgcn_global_load_lds(                              \
                        (gvoid_t*)(s4_ + rr_ * 64 + lane),                         \
                        (lvoid_t*)(lb_ + (size_t)rr_ * 256), 16, 0, 0);            \
            }                                                                      \
        } while (0)

    if (c0 < c1) {
        ISSUE(c0, 0);                              // prologue
        for (int k = c0; k < c1; ++k) {
            const int cur = (k - c0) & 1;
            if (k + 1 < c1) {
                ISSUE(k + 1, cur ^ 1);
                // wait for chunk k's loads (and older stores); leave chunk k+1's streaming
                if (wave == 0) asm volatile("s_waitcnt vmcnt(15)" ::: "memory");
                else           asm volatile("s_waitcnt vmcnt(14)" ::: "memory");
            } else {
                asm volatile("s_waitcnt vmcnt(0)" ::: "memory");
            }
            __builtin_amdgcn_s_barrier();
            __builtin_amdgcn_sched_barrier(0);

            // ---- per-row LZC (one thread per row) ----
            const uint32_t* rw = &s_in[cur][tid * NBITS];  // stride 57: 2-way free
            uint32_t mlo = 0u, mhi = 0u;
            #pragma unroll
            for (int i = 0; i < 32; ++i)
                mlo |= ((rw[i] >> 29) & 1u) << i;          // 0x3F800000 vs 0: bit 29
            #pragma unroll
            for (int i = 32; i < NBITS; ++i)
                mhi |= ((rw[i] >> 29) & 1u) << (i - 32);
            const int lzc = mlo ? (__ffs(mlo) - 1) : (mhi ? (31 + __ffs(mhi)) : NBITS);

            float f[6];
            #pragma unroll
            for (int j = 0; j < 6; ++j)
                f[j] = (float)((lzc >> (5 - j)) & 1);
            float2* o = (float2*)(out + (size_t)(k * RPB + tid) * 6);  // 24B/row, 8B-aligned
            o[0] = make_float2(f[0], f[1]);
            o[1] = make_float2(f[2], f[3]);
            o[2] = make_float2(f[4], f[5]);

            __builtin_amdgcn_sched_barrier(0);
            __builtin_amdgcn_s_barrier();              // reads done before buf[cur] is re-staged
        }
    }

    // ---- tail rows (nrows % RPB), handled by the last block with plain loads ----
    if (b == nb - 1) {
        for (int row = nchunks * RPB + tid; row < nrows; row += 256) {
            const uint32_t* rw = X + (size_t)row * NBITS;
            uint32_t mlo = 0u, mhi = 0u;
            #pragma unroll
            for (int i = 0; i < 32; ++i)
                mlo |= ((rw[i] >> 29) & 1u) << i;
            #pragma unroll
            for (int i = 32; i < NBITS; ++i)
                mhi |= ((rw[i] >> 29) & 1u) << (i - 32);
            const int lzc = mlo ? (__ffs(mlo) - 1) : (mhi ? (31 + __ffs(mhi)) : NBITS);
            float2* o = (float2*)(out + (size_t)row * 6);
            o[0] = make_float2((float)((lzc >> 5) & 1), (float)((lzc >> 4) & 1));
            o[1] = make_float2((float)((lzc >> 3) & 1), (float)((lzc >> 2) & 1));
            o[2] = make_float2((float)((lzc >> 1) & 1), (float)(lzc & 1));
        }
    }
    #undef ISSUE
}

extern "C" void kernel_launch(void* const* d_in, const int* in_sizes, int n_in,
                              void* d_out, int out_size, void* d_ws, size_t ws_size,
                              hipStream_t stream) {
    const uint32_t* X = (const uint32_t*)d_in[0];
    float* out = (float*)d_out;
    const int nrows = in_sizes[0] / NBITS;
    const int nchunks = nrows / RPB;          // full 256-row chunks
    lzc57_kernel<<<256, 256, 0, stream>>>(X, out, nrows, nchunks);
}

// Round 5
// 97.560 us; speedup vs baseline: 1.5069x; 1.1172x over previous
//
#include <hip/hip_runtime.h>
#include <stdint.h>

#define NBITS 57
#define RPB   128                     // rows per block (2e6 % 128 == 0 -> no tail block)
#define NW    (RPB * NBITS)           // 7296 words per chunk
#define N4F   ((NW / 4 / 64) * 64)    // 1792 uint4 in full 64-lane rounds (28 rounds)
#define REM   (NW - N4F * 4)          // 128 remaining words

typedef const __attribute__((address_space(1))) void gvoid_t;
typedef __attribute__((address_space(3))) void       lvoid_t;

__global__ __launch_bounds__(256) void lzc57_kernel(const uint32_t* __restrict__ X,
                                                    float* __restrict__ out,
                                                    int nrows) {
    __shared__ uint32_t s_in[NW];       // 29184 B
    __shared__ float    s_out[RPB * 6]; // 3072 B  -> total 32256 B = 5 blocks/CU
    const int tid  = threadIdx.x;
    const int wave = tid >> 6;
    const int lane = tid & 63;
    const int row0 = blockIdx.x * RPB;
    const int rows = min(RPB, nrows - row0);
    const uint32_t* src = X + (size_t)row0 * NBITS;

    // ---- stage input: 28 full async rounds (7 per wave) + 128-word manual tail ----
    if (rows == RPB) {
        const uint4* src4 = (const uint4*)src;
        #pragma unroll
        for (int i = 0; i < 7; ++i) {
            const int rr = wave + 4 * i;              // round index
            __builtin_amdgcn_global_load_lds(
                (gvoid_t*)(src4 + rr * 64 + lane),    // per-lane global source (1KB/wave)
                (lvoid_t*)(s_in + (size_t)rr * 256),  // wave-uniform LDS base
                16, 0, 0);
        }
        if (tid < REM) s_in[N4F * 4 + tid] = src[N4F * 4 + tid];
    } else {
        const int nwords = rows * NBITS;
        for (int i = tid; i < nwords; i += 256) s_in[i] = src[i];
    }
    __syncthreads();   // compiler drains vmcnt/lgkmcnt before s_barrier

    // ---- per-row LZC (threads 0..127, one row each) ----
    if (tid < rows) {
        const uint32_t* r = &s_in[tid * NBITS];   // stride 57: gcd(57,32)=1 -> 2-way, free
        uint32_t mlo = 0u, mhi = 0u;
        #pragma unroll
        for (int i = 0; i < 32; ++i)
            mlo |= ((r[i] >> 29) & 1u) << i;      // words are 0x3F800000 or 0: bit 29
        #pragma unroll
        for (int i = 32; i < NBITS; ++i)
            mhi |= ((r[i] >> 29) & 1u) << (i - 32);
        const int lzc = mlo ? (__ffs(mlo) - 1) : (mhi ? (31 + __ffs(mhi)) : NBITS);
        #pragma unroll
        for (int j = 0; j < 6; ++j)
            s_out[tid * 6 + j] = (float)((lzc >> (5 - j)) & 1);
    }
    __syncthreads();

    // ---- coalesced float4 store of staged output (192 float4 for a full block) ----
    float* dstf = out + (size_t)row0 * 6;
    const int nout = rows * 6;
    const int no4 = nout >> 2;
    const float4* s4 = (const float4*)s_out;
    float4* o4 = (float4*)dstf;
    for (int i = tid; i < no4; i += 256) o4[i] = s4[i];
    for (int i = (no4 << 2) + tid; i < nout; i += 256) dstf[i] = s_out[i];
}

extern "C" void kernel_launch(void* const* d_in, const int* in_sizes, int n_in,
                              void* d_out, int out_size, void* d_ws, size_t ws_size,
                              hipStream_t stream) {
    const uint32_t* X = (const uint32_t*)d_in[0];
    float* out = (float*)d_out;
    const int nrows = in_sizes[0] / NBITS;
    const int blocks = (nrows + RPB - 1) / RPB;
    lzc57_kernel<<<blocks, 256, 0, stream>>>(X, out, nrows);
}